// Round 3
// baseline (38.113 us; speedup 1.0000x reference)
//
#include <hip/hip_runtime.h>

// ExodusNet: per-timestep 32-tap dense projection + LIF scan (membrane subtract).
// x: [N=16384, C=2, H=4, W=4, T=100] f32 (t innermost, chw stride = 100)
// W: [1,2,4,4] f32 (32 taps) -> uniform-address, lands in SGPRs
// out: [N,1,1,1,T] f32 = spikes
//
// Memory-bound: 210 MB read + 6.5 MB write. R1: 38.7 us. R2: 37.3 us (5.8 TB/s,
// ~92% of m13 float4-copy ceiling). R3: float4 loads — lane l<50 owns
// (neuron l/25, t-quad l%25) -> 800 B/wave-instr (2x R2), 16 load instrs
// per neuron (was 32). Tests whether the residual gap is VMEM issue rate.

#define T_STEPS 100
#define CHW     32
#define NPW     2       // neurons per wave
#define NPB     8       // neurons per block (4 waves * NPW)
#define PITCH   104     // multiple of 4 -> 16B-aligned rows for float4 LDS ops

__global__ __launch_bounds__(256, 4)
void exodus_fused(const float* __restrict__ x,
                  const float* __restrict__ W,
                  float* __restrict__ out) {
    __shared__ float s_in[NPB][PITCH];   // weighted input per (neuron, t)
    __shared__ float s_sp[NPB][PITCH];   // spikes per (neuron, t)

    const int tid    = threadIdx.x;
    const int lane   = tid & 63;
    const int wv     = tid >> 6;               // 0..3
    const int n_base = blockIdx.x * NPB;

    // 32 taps, uniform address -> scalar loads / SGPRs.
    float Wr[CHW];
    #pragma unroll
    for (int c = 0; c < CHW; ++c) Wr[c] = W[c];

    // ---- Phase A: weighted[n][t] = sum_c W[c] * x[n][c][t] ----
    // lane l (<50): neuron nl = l/25, t-quad qd = l%25. One float4 per c row:
    // 50 lanes x 16B = 800 B per wave-instruction, 32 instrs per neuron-pair.
    // 4 chunks of 8 rows, 2 register buffers -> loads stay ahead of FMAs.
    if (lane < 50) {
        const int nl = lane / 25;              // 0 or 1
        const int qd = lane - nl * 25;         // t-quad index 0..24
        const float* xp = x + (size_t)(n_base + wv * NPW + nl) * (CHW * T_STEPS)
                        + qd * 4;

        float4 bA[8], bB[8];
        float4 acc = {0.f, 0.f, 0.f, 0.f};

        #pragma unroll
        for (int j = 0; j < 8; ++j)            // chunk0: c = 0..7
            bA[j] = *reinterpret_cast<const float4*>(xp + j * T_STEPS);
        #pragma unroll
        for (int j = 0; j < 8; ++j)            // chunk1: c = 8..15
            bB[j] = *reinterpret_cast<const float4*>(xp + (8 + j) * T_STEPS);

        #pragma unroll
        for (int j = 0; j < 8; ++j) {          // consume chunk0
            acc.x = fmaf(Wr[j], bA[j].x, acc.x);
            acc.y = fmaf(Wr[j], bA[j].y, acc.y);
            acc.z = fmaf(Wr[j], bA[j].z, acc.z);
            acc.w = fmaf(Wr[j], bA[j].w, acc.w);
        }
        #pragma unroll
        for (int j = 0; j < 8; ++j)            // chunk2: c = 16..23
            bA[j] = *reinterpret_cast<const float4*>(xp + (16 + j) * T_STEPS);
        #pragma unroll
        for (int j = 0; j < 8; ++j) {          // consume chunk1
            acc.x = fmaf(Wr[8 + j], bB[j].x, acc.x);
            acc.y = fmaf(Wr[8 + j], bB[j].y, acc.y);
            acc.z = fmaf(Wr[8 + j], bB[j].z, acc.z);
            acc.w = fmaf(Wr[8 + j], bB[j].w, acc.w);
        }
        #pragma unroll
        for (int j = 0; j < 8; ++j)            // chunk3: c = 24..31
            bB[j] = *reinterpret_cast<const float4*>(xp + (24 + j) * T_STEPS);
        #pragma unroll
        for (int j = 0; j < 8; ++j) {          // consume chunk2
            acc.x = fmaf(Wr[16 + j], bA[j].x, acc.x);
            acc.y = fmaf(Wr[16 + j], bA[j].y, acc.y);
            acc.z = fmaf(Wr[16 + j], bA[j].z, acc.z);
            acc.w = fmaf(Wr[16 + j], bA[j].w, acc.w);
        }
        #pragma unroll
        for (int j = 0; j < 8; ++j) {          // consume chunk3
            acc.x = fmaf(Wr[24 + j], bB[j].x, acc.x);
            acc.y = fmaf(Wr[24 + j], bB[j].y, acc.y);
            acc.z = fmaf(Wr[24 + j], bB[j].z, acc.z);
            acc.w = fmaf(Wr[24 + j], bB[j].w, acc.w);
        }

        *reinterpret_cast<float4*>(&s_in[wv * NPW + nl][qd * 4]) = acc;
    }
    __syncthreads();

    // ---- Phase B: LIF scan, sequential in t (nonlinear reset -> serial).
    // Lanes 0..1 of each wave scan the wave's 2 neurons.
    if (lane < NPW) {
        const int nl = wv * NPW + lane;
        const float A = 0.9048374180359595f;   // exp(-1/10) rounded to f32
        const float B = 0.0951625819640404f;   // 1 - alpha
        float v = 0.f;
        #pragma unroll 4
        for (int t = 0; t < T_STEPS; ++t) {
            v = fmaf(A, v, B * s_in[nl][t]);
            const float sp = (v >= 1.0f) ? 1.0f : 0.0f;
            v -= sp;                           // membrane subtract (THR = 1)
            s_sp[nl][t] = sp;
        }
    }
    __syncthreads();

    // ---- Phase C: one dense float4 write of the block's 3200 B output slice.
    if (tid < NPB * T_STEPS / 4) {             // 200 lanes
        const int t4 = tid * 4;
        const int n  = t4 / T_STEPS;
        const int t  = t4 - n * T_STEPS;       // multiple of 4; 100%4==0 -> no row cross
        *reinterpret_cast<float4*>(out + (size_t)n_base * T_STEPS + t4) =
            *reinterpret_cast<const float4*>(&s_sp[n][t]);
    }
}

extern "C" void kernel_launch(void* const* d_in, const int* in_sizes, int n_in,
                              void* d_out, int out_size, void* d_ws, size_t ws_size,
                              hipStream_t stream) {
    const float* x = (const float*)d_in[0];
    const float* W = (const float*)d_in[1];
    float* out = (float*)d_out;

    const int N = in_sizes[0] / (CHW * T_STEPS);   // 16384
    const int grid = N / NPB;                      // 2048 blocks
    exodus_fused<<<grid, 256, 0, stream>>>(x, W, out);
}